// Round 1
// baseline (1218.891 us; speedup 1.0000x reference)
//
#include <hip/hip_runtime.h>
#include <math.h>

// Problem constants
#define NPTS   131072      // RN*SN = 1024*128
#define NVIEW  4
#define IMH    256
#define IMW    256

// Workspace layout (float offsets)
#define WS_FEATT   0u                  // 4*65536*32  = 8388608
#define WS_IMGT    8388608u            // 4*65536*4   = 1048576
#define WS_X1      9437184u            // NPTS*4*32   = 16777216  (feat tokens -> later view features, in place)
#define WS_XR      26214400u           // NPTS*40     = 5242880   (ray-transformer sequence, in place through K3)
#define WS_MSG     31457280u           // NPTS*40     = 5242880
#define WS_RGB     36700160u           // NPTS*12
#define WS_DIR     38273024u           // NPTS*12
#define WS_MASK    39845888u           // NPTS*4
// total: 40370176 floats = 161.5 MB

__device__ __forceinline__ float elup1(float t) { return t > 0.f ? t + 1.f : expf(t); }

// ---------------------------------------------------------------------------
// K0: (v,c,y,x) -> (v,y,x,c) transpose for feat (32ch) and rgb (3ch, padded 4)
// ---------------------------------------------------------------------------
__global__ __launch_bounds__(256) void k0_transpose(
    const float* __restrict__ feat, const float* __restrict__ img,
    float* __restrict__ featT, float* __restrict__ imgT)
{
    int tid = blockIdx.x * 256 + threadIdx.x;          // 262144 = 4*65536
    int v = tid >> 16, pix = tid & 65535;
    float buf[32];
#pragma unroll
    for (int c = 0; c < 32; ++c)
        buf[c] = feat[((size_t)(v * 32 + c) << 16) + pix];
    float4* dst = (float4*)(featT + ((size_t)tid << 5));
#pragma unroll
    for (int q = 0; q < 8; ++q)
        dst[q] = make_float4(buf[4*q], buf[4*q+1], buf[4*q+2], buf[4*q+3]);
    float4 rgb;
    rgb.x = img[((size_t)(v * 3 + 0) << 16) + pix];
    rgb.y = img[((size_t)(v * 3 + 1) << 16) + pix];
    rgb.z = img[((size_t)(v * 3 + 2) << 16) + pix];
    rgb.w = 0.f;
    *(float4*)(imgT + ((size_t)tid << 2)) = rgb;
}

// ---------------------------------------------------------------------------
// K1: per (point, view): dir_relative, pip (-> out2), bilinear sample feat+rgb,
//     mask. Writes X1[p][v][32], rgb[p][12], dir[p][12], mask[p][4].
// ---------------------------------------------------------------------------
__global__ __launch_bounds__(256) void k1_geom_sample(
    const float* __restrict__ p3d, const float* __restrict__ rpi,
    const float* __restrict__ spi, const float* __restrict__ sp,
    const float* __restrict__ featT, const float* __restrict__ imgT,
    float* __restrict__ x1, float* __restrict__ rgbw,
    float* __restrict__ dirw, float* __restrict__ maskw,
    float* __restrict__ outpip)
{
    int tid = blockIdx.x * 256 + threadIdx.x;          // 524288
    int p = tid >> 2, v = tid & 3;
    float X = p3d[p * 3 + 0], Y = p3d[p * 3 + 1], Z = p3d[p * 3 + 2];

    // dir_relative = normalize(P - t_ref) - normalize(P - t_src[v])
    float a0 = X - rpi[3], a1 = Y - rpi[7], a2 = Z - rpi[11];
    float na = sqrtf(a0 * a0 + a1 * a1 + a2 * a2);
    a0 /= na; a1 /= na; a2 /= na;
    const float* sv = spi + v * 16;
    float b0 = X - sv[3], b1 = Y - sv[7], b2 = Z - sv[11];
    float nb = sqrtf(b0 * b0 + b1 * b1 + b2 * b2);
    b0 /= nb; b1 /= nb; b2 /= nb;
    dirw[(size_t)p * 12 + v * 3 + 0] = a0 - b0;
    dirw[(size_t)p * 12 + v * 3 + 1] = a1 - b1;
    dirw[(size_t)p * 12 + v * 3 + 2] = a2 - b2;

    // pip = P @ [X,Y,Z,1]
    const float* P = sp + v * 16;
    float pip0 = P[0] * X + P[1] * Y + P[2]  * Z + P[3];
    float pip1 = P[4] * X + P[5] * Y + P[6]  * Z + P[7];
    float pip2 = P[8] * X + P[9] * Y + P[10] * Z + P[11];
    outpip[(size_t)(v * 3 + 0) * NPTS + p] = pip0;
    outpip[(size_t)(v * 3 + 1) * NPTS + p] = pip1;
    outpip[(size_t)(v * 3 + 2) * NPTS + p] = pip2;

    float gx = pip0 / pip2, gy = pip1 / pip2;
    float inb = (gx >= 0.f && gx <= 255.f && gy >= 0.f && gy <= 255.f) ? 1.f : 0.f;
    float mvd = pip2 > 0.f ? 1.f : 0.f;
    maskw[(size_t)p * 4 + v] = inb * mvd;

    float x0f = floorf(gx), y0f = floorf(gy);
    float wx = gx - x0f, wy = gy - y0f;
    int ix0 = (int)x0f, iy0 = (int)y0f;
    float tw[4] = { (1.f-wx)*(1.f-wy), wx*(1.f-wy), (1.f-wx)*wy, wx*wy };
    int tdx[4] = { 0, 1, 0, 1 };
    int tdy[4] = { 0, 0, 1, 1 };

    float facc[32];
#pragma unroll
    for (int c = 0; c < 32; ++c) facc[c] = 0.f;
    float r0 = 0.f, r1 = 0.f, r2 = 0.f;

#pragma unroll
    for (int tno = 0; tno < 4; ++tno) {
        int ix = ix0 + tdx[tno], iy = iy0 + tdy[tno];
        float valid = (ix >= 0 && ix < IMW && iy >= 0 && iy < IMH) ? 1.f : 0.f;
        int cx = min(max(ix, 0), IMW - 1), cy = min(max(iy, 0), IMH - 1);
        float wgt = tw[tno] * valid;
        size_t base = ((size_t)v << 16) + ((size_t)cy << 8) + (size_t)cx;
        const float4* fp = (const float4*)(featT + base * 32);
#pragma unroll
        for (int q = 0; q < 8; ++q) {
            float4 f4 = fp[q];
            facc[4*q+0] += f4.x * wgt; facc[4*q+1] += f4.y * wgt;
            facc[4*q+2] += f4.z * wgt; facc[4*q+3] += f4.w * wgt;
        }
        float4 rp = *(const float4*)(imgT + base * 4);
        r0 += rp.x * wgt; r1 += rp.y * wgt; r2 += rp.z * wgt;
    }

    float4* xd = (float4*)(x1 + ((size_t)p * 4 + v) * 32);
#pragma unroll
    for (int q = 0; q < 8; ++q)
        xd[q] = make_float4(facc[4*q], facc[4*q+1], facc[4*q+2], facc[4*q+3]);
    rgbw[(size_t)p * 12 + v * 3 + 0] = r0;
    rgbw[(size_t)p * 12 + v * 3 + 1] = r1;
    rgbw[(size_t)p * 12 + v * 3 + 2] = r2;
}

// ---------------------------------------------------------------------------
// K2: fused LoFTR self-layer 1 (d=32, L=5, 8 heads x dim4).
// Block = 256 threads = 8 points x 32 column-lanes. All weights in LDS.
// Writes: XR[p][0..31] = token0 out, XR[p][32..39] = posenc; X1[p][v] = view feats.
// ---------------------------------------------------------------------------
__global__ __launch_bounds__(256) void k2_loftr1(
    float* __restrict__ x1g, const float* __restrict__ vtok,
    const float* __restrict__ Wq, const float* __restrict__ Wk,
    const float* __restrict__ Wv, const float* __restrict__ Wm,
    const float* __restrict__ g1, const float* __restrict__ b1,
    const float* __restrict__ W1, const float* __restrict__ W2,
    const float* __restrict__ g2, const float* __restrict__ b2,
    float* __restrict__ xr)
{
    // LDS: Wq 0, Wk 1024, Wv 2048, Wm 3072, W1 4096(4096), W2 8192(2048),
    //      g1 10240, b1 10272, g2 10304, b2 10336, vtok 10368; scratch at 10400.
    __shared__ float sm[10400 + 8 * 640];
    int tid = threadIdx.x;
    for (int i = tid; i < 1024; i += 256) {
        sm[i] = Wq[i]; sm[1024 + i] = Wk[i]; sm[2048 + i] = Wv[i]; sm[3072 + i] = Wm[i];
    }
    for (int i = tid; i < 4096; i += 256) sm[4096 + i] = W1[i];
    for (int i = tid; i < 2048; i += 256) sm[8192 + i] = W2[i];
    if (tid < 32) {
        sm[10240 + tid] = g1[tid]; sm[10272 + tid] = b1[tid];
        sm[10304 + tid] = g2[tid]; sm[10336 + tid] = b2[tid];
        sm[10368 + tid] = vtok[tid];
    }
    __syncthreads();

    int pp = tid >> 5, c = tid & 31;
    float* S = sm + 10400 + pp * 640;   // x:0, A:160 (Q/msg), B:320 (K/h-lo), C:480 (V/attn/h-hi)

    for (int g = blockIdx.x; g < NPTS / 8; g += gridDim.x) {
        int p = g * 8 + pp;
        // ---- load x: [token0=view_token ; 4 view feats]
        S[c] = sm[10368 + c];
#pragma unroll
        for (int vv = 0; vv < 4; ++vv)
            S[(1 + vv) * 32 + c] = x1g[((size_t)p * 4 + vv) * 32 + c];
        __syncthreads();

        // ---- q,k,v projections (column c), elu+1 on q,k
        {
            float qa[5], ka[5], va[5];
#pragma unroll
            for (int l = 0; l < 5; ++l) { qa[l] = 0.f; ka[l] = 0.f; va[l] = 0.f; }
            for (int kk = 0; kk < 32; ++kk) {
                float wq = sm[kk * 32 + c], wk = sm[1024 + kk * 32 + c], wv = sm[2048 + kk * 32 + c];
#pragma unroll
                for (int l = 0; l < 5; ++l) {
                    float xv = S[l * 32 + kk];
                    qa[l] += xv * wq; ka[l] += xv * wk; va[l] += xv * wv;
                }
            }
#pragma unroll
            for (int l = 0; l < 5; ++l) {
                S[160 + l * 32 + c] = elup1(qa[l]);
                S[320 + l * 32 + c] = elup1(ka[l]);
                S[480 + l * 32 + c] = va[l];
            }
        }
        __syncthreads();

        // ---- linear attention; c -> (h=c>>2, d=c&3); out into C (own column)
        {
            int hb = (c >> 2) << 2;
            float Vl[5], Ke[5][4];
#pragma unroll
            for (int s2 = 0; s2 < 5; ++s2) {
                Vl[s2] = S[480 + s2 * 32 + c];
#pragma unroll
                for (int e = 0; e < 4; ++e) Ke[s2][e] = S[320 + s2 * 32 + hb + e];
            }
            float kv[4] = {0,0,0,0}, ks[4] = {0,0,0,0};
#pragma unroll
            for (int s2 = 0; s2 < 5; ++s2)
#pragma unroll
                for (int e = 0; e < 4; ++e) { kv[e] += Ke[s2][e] * Vl[s2]; ks[e] += Ke[s2][e]; }
#pragma unroll
            for (int l = 0; l < 5; ++l) {
                float q0 = S[160 + l * 32 + hb], q1 = S[160 + l * 32 + hb + 1];
                float q2 = S[160 + l * 32 + hb + 2], q3 = S[160 + l * 32 + hb + 3];
                float den = q0*ks[0] + q1*ks[1] + q2*ks[2] + q3*ks[3] + 1e-6f;
                float o   = q0*kv[0] + q1*kv[1] + q2*kv[2] + q3*kv[3];
                S[480 + l * 32 + c] = o / den;   // (1/L and *L cancel exactly)
            }
        }
        __syncthreads();

        // ---- msg = attn @ Wm, then LN1 (across 32 lanes) -> into A
        {
            float ma[5] = {0,0,0,0,0};
            for (int kk = 0; kk < 32; ++kk) {
                float w = sm[3072 + kk * 32 + c];
#pragma unroll
                for (int l = 0; l < 5; ++l) ma[l] += S[480 + l * 32 + kk] * w;
            }
#pragma unroll
            for (int l = 0; l < 5; ++l) {
                float s1 = ma[l], s2v = ma[l] * ma[l];
#pragma unroll
                for (int off = 16; off > 0; off >>= 1) {
                    s1  += __shfl_xor(s1,  off, 32);
                    s2v += __shfl_xor(s2v, off, 32);
                }
                float m  = s1 * (1.f / 32.f);
                float va = s2v * (1.f / 32.f) - m * m;
                float rs = rsqrtf(va + 1e-5f);
                S[160 + l * 32 + c] = (ma[l] - m) * rs * sm[10240 + c] + sm[10272 + c];
            }
        }
        __syncthreads();

        // ---- FFN hidden: h = relu([x,msg] @ W1), h into B:C (stride 64)
        {
            float hA[5] = {0,0,0,0,0}, hB[5] = {0,0,0,0,0};
            for (int kk = 0; kk < 32; ++kk) {
                float wa = sm[4096 + kk * 64 + c],        wb2 = sm[4096 + kk * 64 + c + 32];
                float wc = sm[4096 + (32 + kk) * 64 + c], wd  = sm[4096 + (32 + kk) * 64 + c + 32];
#pragma unroll
                for (int l = 0; l < 5; ++l) {
                    float xv = S[l * 32 + kk], mv = S[160 + l * 32 + kk];
                    hA[l] += xv * wa + mv * wc;
                    hB[l] += xv * wb2 + mv * wd;
                }
            }
#pragma unroll
            for (int l = 0; l < 5; ++l) {
                S[320 + l * 64 + c]      = fmaxf(hA[l], 0.f);
                S[320 + l * 64 + c + 32] = fmaxf(hB[l], 0.f);
            }
        }
        __syncthreads();

        // ---- out = h @ W2, LN2, residual, store
        {
            float oa[5] = {0,0,0,0,0};
            for (int kk = 0; kk < 64; ++kk) {
                float w = sm[8192 + kk * 32 + c];
#pragma unroll
                for (int l = 0; l < 5; ++l) oa[l] += S[320 + l * 64 + kk] * w;
            }
#pragma unroll
            for (int l = 0; l < 5; ++l) {
                float s1 = oa[l], s2v = oa[l] * oa[l];
#pragma unroll
                for (int off = 16; off > 0; off >>= 1) {
                    s1  += __shfl_xor(s1,  off, 32);
                    s2v += __shfl_xor(s2v, off, 32);
                }
                float m  = s1 * (1.f / 32.f);
                float va = s2v * (1.f / 32.f) - m * m;
                float rs = rsqrtf(va + 1e-5f);
                float y  = S[l * 32 + c] + (oa[l] - m) * rs * sm[10304 + c] + sm[10336 + c];
                if (l == 0) xr[(size_t)p * 40 + c] = y;
                else        x1g[((size_t)p * 4 + (l - 1)) * 32 + c] = y;
            }
            if (c < 8) {   // positional encoding, position s = p & 127
                int sidx = p & 127;
                float den = (c < 2) ? 1.f : (c < 4) ? 10.f : (c < 6) ? 100.f : 1000.f;
                float arg = (float)sidx / den;
                xr[(size_t)p * 40 + 32 + c] = (c & 1) ? cosf(arg) : sinf(arg);
            }
        }
        __syncthreads();
    }
}

// ---------------------------------------------------------------------------
// K3a: layer-2 attention half. One ray (L=128, d=40, 8 heads x dim5) per block.
// x read from global (L1/L2 resident). Writes msg (post-Wm, post-LN1).
// ---------------------------------------------------------------------------
__global__ __launch_bounds__(320) void k3a_attn(
    const float* __restrict__ xr,
    const float* __restrict__ Wq, const float* __restrict__ Wk,
    const float* __restrict__ Wv, const float* __restrict__ Wm,
    const float* __restrict__ g1, const float* __restrict__ b1,
    float* __restrict__ msg)
{
    __shared__ float kb[5120];   // K -> Q -> msgpre
    __shared__ float vb[5120];   // V -> attn-out
    __shared__ float wb[1600];
    __shared__ float kvb[200];
    __shared__ float ksb[40];
    int t = threadIdx.x, r = blockIdx.x;
    const float* xbase = xr + (size_t)r * 5120;
    int lg = t / 40, c = t % 40;

    // K projection (elu+1)
    for (int i = t; i < 1600; i += 320) wb[i] = Wk[i];
    __syncthreads();
    {
        float acc[16];
#pragma unroll
        for (int i = 0; i < 16; ++i) acc[i] = 0.f;
        for (int kk = 0; kk < 40; ++kk) {
            float w = wb[kk * 40 + c];
#pragma unroll
            for (int i = 0; i < 16; ++i) acc[i] += xbase[(lg * 16 + i) * 40 + kk] * w;
        }
#pragma unroll
        for (int i = 0; i < 16; ++i) kb[(lg * 16 + i) * 40 + c] = elup1(acc[i]);
    }
    __syncthreads();
    // V projection
    for (int i = t; i < 1600; i += 320) wb[i] = Wv[i];
    __syncthreads();
    {
        float acc[16];
#pragma unroll
        for (int i = 0; i < 16; ++i) acc[i] = 0.f;
        for (int kk = 0; kk < 40; ++kk) {
            float w = wb[kk * 40 + c];
#pragma unroll
            for (int i = 0; i < 16; ++i) acc[i] += xbase[(lg * 16 + i) * 40 + kk] * w;
        }
#pragma unroll
        for (int i = 0; i < 16; ++i) vb[(lg * 16 + i) * 40 + c] = acc[i];
    }
    __syncthreads();
    // KV[h][e][d], Ksum[h][e]
    if (t < 200) {
        int h = t / 25, e = (t / 5) % 5, d = t % 5;
        float kv = 0.f, ks = 0.f;
        for (int s2 = 0; s2 < 128; ++s2) {
            float kvv = kb[s2 * 40 + h * 5 + e];
            float vv  = vb[s2 * 40 + h * 5 + d];
            kv += kvv * vv; ks += kvv;
        }
        kvb[t] = kv;
        if (d == 0) ksb[h * 5 + e] = ks;
    }
    __syncthreads();
    // Q projection (elu+1) into kb
    for (int i = t; i < 1600; i += 320) wb[i] = Wq[i];
    __syncthreads();
    {
        float acc[16];
#pragma unroll
        for (int i = 0; i < 16; ++i) acc[i] = 0.f;
        for (int kk = 0; kk < 40; ++kk) {
            float w = wb[kk * 40 + c];
#pragma unroll
            for (int i = 0; i < 16; ++i) acc[i] += xbase[(lg * 16 + i) * 40 + kk] * w;
        }
#pragma unroll
        for (int i = 0; i < 16; ++i) kb[(lg * 16 + i) * 40 + c] = elup1(acc[i]);
    }
    __syncthreads();
    // attention out into vb
    {
        int h = c / 5, d = c % 5;
#pragma unroll 4
        for (int i = 0; i < 16; ++i) {
            int l = lg * 16 + i;
            float den = 1e-6f, o = 0.f;
#pragma unroll
            for (int e = 0; e < 5; ++e) {
                float q = kb[l * 40 + h * 5 + e];
                den += q * ksb[h * 5 + e];
                o   += q * kvb[h * 25 + e * 5 + d];
            }
            vb[l * 40 + c] = o / den;
        }
    }
    __syncthreads();
    // msgpre = attn @ Wm into kb
    for (int i = t; i < 1600; i += 320) wb[i] = Wm[i];
    __syncthreads();
    {
        float acc[16];
#pragma unroll
        for (int i = 0; i < 16; ++i) acc[i] = 0.f;
        for (int kk = 0; kk < 40; ++kk) {
            float w = wb[kk * 40 + c];
#pragma unroll
            for (int i = 0; i < 16; ++i) acc[i] += vb[(lg * 16 + i) * 40 + kk] * w;
        }
#pragma unroll
        for (int i = 0; i < 16; ++i) kb[(lg * 16 + i) * 40 + c] = acc[i];
    }
    __syncthreads();
    // LN1 per token, store msg
    if (t < 128) {
        float s1 = 0.f, s2v = 0.f;
        for (int j = 0; j < 40; ++j) { float x = kb[t * 40 + j]; s1 += x; s2v += x * x; }
        float m = s1 * (1.f / 40.f), va = s2v * (1.f / 40.f) - m * m;
        float rs = rsqrtf(va + 1e-5f);
        for (int j = 0; j < 40; ++j)
            msg[((size_t)r * 128 + t) * 40 + j] = (kb[t * 40 + j] - m) * rs * g1[j] + b1[j];
    }
}

// ---------------------------------------------------------------------------
// K3b: layer-2 FFN half: y = x + LN2(relu([x,msg]@W1)@W2). In-place on xr.
// ---------------------------------------------------------------------------
__global__ __launch_bounds__(320) void k3b_ffn(
    float* __restrict__ xr, const float* __restrict__ msg,
    const float* __restrict__ W1, const float* __restrict__ W2,
    const float* __restrict__ g2, const float* __restrict__ b2)
{
    __shared__ float hb[10240];
    __shared__ float wb[3200];
    int t = threadIdx.x, r = blockIdx.x;
    int lg = t / 40, c = t % 40;
    const float* xbase = xr + (size_t)r * 5120;
    const float* mbase = msg + (size_t)r * 5120;

    float hA[16], hB[16];
#pragma unroll
    for (int i = 0; i < 16; ++i) { hA[i] = 0.f; hB[i] = 0.f; }

    for (int i = t; i < 3200; i += 320) wb[i] = W1[i];           // rows 0..39 (x part)
    __syncthreads();
    for (int kk = 0; kk < 40; ++kk) {
        float wa = wb[kk * 80 + c], wbb = wb[kk * 80 + c + 40];
#pragma unroll
        for (int i = 0; i < 16; ++i) {
            float xv = xbase[(lg * 16 + i) * 40 + kk];
            hA[i] += xv * wa; hB[i] += xv * wbb;
        }
    }
    __syncthreads();
    for (int i = t; i < 3200; i += 320) wb[i] = W1[3200 + i];    // rows 40..79 (msg part)
    __syncthreads();
    for (int kk = 0; kk < 40; ++kk) {
        float wa = wb[kk * 80 + c], wbb = wb[kk * 80 + c + 40];
#pragma unroll
        for (int i = 0; i < 16; ++i) {
            float mv = mbase[(lg * 16 + i) * 40 + kk];
            hA[i] += mv * wa; hB[i] += mv * wbb;
        }
    }
#pragma unroll
    for (int i = 0; i < 16; ++i) {
        hb[(lg * 16 + i) * 80 + c]      = fmaxf(hA[i], 0.f);
        hb[(lg * 16 + i) * 80 + c + 40] = fmaxf(hB[i], 0.f);
    }
    __syncthreads();
    for (int i = t; i < 3200; i += 320) wb[i] = W2[i];
    __syncthreads();
    float oa[16];
#pragma unroll
    for (int i = 0; i < 16; ++i) oa[i] = 0.f;
    for (int kk = 0; kk < 80; ++kk) {
        float w = wb[kk * 40 + c];
#pragma unroll
        for (int i = 0; i < 16; ++i) oa[i] += hb[(lg * 16 + i) * 80 + kk] * w;
    }
    __syncthreads();
#pragma unroll
    for (int i = 0; i < 16; ++i) hb[(lg * 16 + i) * 40 + c] = oa[i];   // opre
    __syncthreads();
    if (t < 128) {
        float s1 = 0.f, s2v = 0.f;
        for (int j = 0; j < 40; ++j) { float x = hb[t * 40 + j]; s1 += x; s2v += x * x; }
        float m = s1 * (1.f / 40.f), va = s2v * (1.f / 40.f) - m * m;
        float rs = rsqrtf(va + 1e-5f);
        for (int j = 0; j < 40; ++j) {
            float y = xbase[t * 40 + j] + (hb[t * 40 + j] - m) * rs * g2[j] + b2[j];
            xr[(size_t)r * 5120 + t * 40 + j] = y;
        }
    }
}

// ---------------------------------------------------------------------------
// K4: srdf head: relu(x@W1+b1) -> relu(@W2+b2) -> @W3+b3. One thread/point.
// ---------------------------------------------------------------------------
__global__ __launch_bounds__(256) void k4_dm(
    const float* __restrict__ xr,
    const float* __restrict__ W1, const float* __restrict__ b1,
    const float* __restrict__ W2, const float* __restrict__ b2,
    const float* __restrict__ W3, const float* __restrict__ b3,
    float* __restrict__ out1)
{
    __shared__ float s[1857];  // W1 0(1280), b1 1280, W2 1312(512), b2 1824, W3 1840, b3 1856
    int t = threadIdx.x;
    for (int i = t; i < 1280; i += 256) s[i] = W1[i];
    if (t < 32) s[1280 + t] = b1[t];
    for (int i = t; i < 512; i += 256) s[1312 + i] = W2[i];
    if (t < 16) { s[1824 + t] = b2[t]; s[1840 + t] = W3[t]; }
    if (t == 0) s[1856] = b3[0];
    __syncthreads();

    int p = blockIdx.x * 256 + t;
    float x[40];
    const float4* xp = (const float4*)(xr + (size_t)p * 40);
#pragma unroll
    for (int i = 0; i < 10; ++i) {
        float4 v4 = xp[i];
        x[4*i] = v4.x; x[4*i+1] = v4.y; x[4*i+2] = v4.z; x[4*i+3] = v4.w;
    }
    float h1[32];
#pragma unroll
    for (int j = 0; j < 32; ++j) h1[j] = s[1280 + j];
    for (int k = 0; k < 40; ++k) {
        float xv = x[k];
#pragma unroll
        for (int j = 0; j < 32; ++j) h1[j] += xv * s[k * 32 + j];
    }
#pragma unroll
    for (int j = 0; j < 32; ++j) h1[j] = fmaxf(h1[j], 0.f);
    float h2[16];
#pragma unroll
    for (int j = 0; j < 16; ++j) h2[j] = s[1824 + j];
    for (int k = 0; k < 32; ++k) {
        float hv = h1[k];
#pragma unroll
        for (int j = 0; j < 16; ++j) h2[j] += hv * s[1312 + k * 16 + j];
    }
    float o = s[1856];
#pragma unroll
    for (int j = 0; j < 16; ++j) o += fmaxf(h2[j], 0.f) * s[1840 + j];
    out1[p] = o;
}

// ---------------------------------------------------------------------------
// K5: rw head + masked softmax over views + radiance blend. One thread/point.
// ---------------------------------------------------------------------------
__global__ __launch_bounds__(256) void k5_rw(
    const float* __restrict__ vf, const float* __restrict__ dirw,
    const float* __restrict__ maskw, const float* __restrict__ rgbw,
    const float* __restrict__ W1, const float* __restrict__ b1,
    const float* __restrict__ W2, const float* __restrict__ b2,
    const float* __restrict__ W3, const float* __restrict__ b3,
    float* __restrict__ out0)
{
    __shared__ float s[721];  // W1 0(560), b1 560, W2 576(128), b2 704, W3 712, b3 720
    int t = threadIdx.x;
    for (int i = t; i < 560; i += 256) s[i] = W1[i];
    if (t < 16) s[560 + t] = b1[t];
    if (t < 128) s[576 + t] = W2[t];
    if (t < 8) { s[704 + t] = b2[t]; s[712 + t] = W3[t]; }
    if (t == 0) s[720] = b3[0];
    __syncthreads();

    int p = blockIdx.x * 256 + t;
    float xw[4];
#pragma unroll
    for (int v = 0; v < 4; ++v) {
        float in[35];
        const float4* vp = (const float4*)(vf + ((size_t)p * 4 + v) * 32);
#pragma unroll
        for (int q = 0; q < 8; ++q) {
            float4 f4 = vp[q];
            in[4*q] = f4.x; in[4*q+1] = f4.y; in[4*q+2] = f4.z; in[4*q+3] = f4.w;
        }
        in[32] = dirw[(size_t)p * 12 + v * 3 + 0];
        in[33] = dirw[(size_t)p * 12 + v * 3 + 1];
        in[34] = dirw[(size_t)p * 12 + v * 3 + 2];
        float h1[16];
#pragma unroll
        for (int j = 0; j < 16; ++j) h1[j] = s[560 + j];
        for (int k = 0; k < 35; ++k) {
            float xv = in[k];
#pragma unroll
            for (int j = 0; j < 16; ++j) h1[j] += xv * s[k * 16 + j];
        }
        float h2[8];
#pragma unroll
        for (int j = 0; j < 8; ++j) h2[j] = s[704 + j];
        for (int k = 0; k < 16; ++k) {
            float hv = fmaxf(h1[k], 0.f);
#pragma unroll
            for (int j = 0; j < 8; ++j) h2[j] += hv * s[576 + k * 8 + j];
        }
        float o = s[720];
#pragma unroll
        for (int j = 0; j < 8; ++j) o += fmaxf(h2[j], 0.f) * s[712 + j];
        xw[v] = (maskw[(size_t)p * 4 + v] == 0.f) ? -1e9f : o;
    }
    float m = fmaxf(fmaxf(xw[0], xw[1]), fmaxf(xw[2], xw[3]));
    float e0 = expf(xw[0] - m), e1 = expf(xw[1] - m), e2 = expf(xw[2] - m), e3 = expf(xw[3] - m);
    float inv = 1.f / (e0 + e1 + e2 + e3);
    float w4[4] = { e0 * inv, e1 * inv, e2 * inv, e3 * inv };
    float r0 = 0.f, r1 = 0.f, r2 = 0.f;
#pragma unroll
    for (int v = 0; v < 4; ++v) {
        r0 += rgbw[(size_t)p * 12 + v * 3 + 0] * w4[v];
        r1 += rgbw[(size_t)p * 12 + v * 3 + 1] * w4[v];
        r2 += rgbw[(size_t)p * 12 + v * 3 + 2] * w4[v];
    }
    out0[(size_t)p * 3 + 0] = r0;
    out0[(size_t)p * 3 + 1] = r1;
    out0[(size_t)p * 3 + 2] = r2;
}

// ---------------------------------------------------------------------------
extern "C" void kernel_launch(void* const* d_in, const int* in_sizes, int n_in,
                              void* d_out, int out_size, void* d_ws, size_t ws_size,
                              hipStream_t stream) {
    (void)in_sizes; (void)n_in; (void)out_size; (void)ws_size;
    const float* p3d   = (const float*)d_in[0];
    const float* imgs  = (const float*)d_in[1];
    const float* feat  = (const float*)d_in[2];
    const float* rpi   = (const float*)d_in[3];
    const float* spi   = (const float*)d_in[4];
    const float* sp    = (const float*)d_in[5];
    const float* vtok  = (const float*)d_in[6];
    const float* vtWq  = (const float*)d_in[7];
    const float* vtWk  = (const float*)d_in[8];
    const float* vtWv  = (const float*)d_in[9];
    const float* vtWm  = (const float*)d_in[10];
    const float* vtg1  = (const float*)d_in[11];
    const float* vtb1  = (const float*)d_in[12];
    const float* vtW1  = (const float*)d_in[13];
    const float* vtW2  = (const float*)d_in[14];
    const float* vtg2  = (const float*)d_in[15];
    const float* vtb2  = (const float*)d_in[16];
    const float* rtWq  = (const float*)d_in[17];
    const float* rtWk  = (const float*)d_in[18];
    const float* rtWv  = (const float*)d_in[19];
    const float* rtWm  = (const float*)d_in[20];
    const float* rtg1  = (const float*)d_in[21];
    const float* rtb1  = (const float*)d_in[22];
    const float* rtW1  = (const float*)d_in[23];
    const float* rtW2  = (const float*)d_in[24];
    const float* rtg2  = (const float*)d_in[25];
    const float* rtb2  = (const float*)d_in[26];
    const float* dmW1  = (const float*)d_in[27];
    const float* dmb1  = (const float*)d_in[28];
    const float* dmW2  = (const float*)d_in[29];
    const float* dmb2  = (const float*)d_in[30];
    const float* dmW3  = (const float*)d_in[31];
    const float* dmb3  = (const float*)d_in[32];
    const float* rwW1  = (const float*)d_in[33];
    const float* rwb1  = (const float*)d_in[34];
    const float* rwW2  = (const float*)d_in[35];
    const float* rwb2  = (const float*)d_in[36];
    const float* rwW3  = (const float*)d_in[37];
    const float* rwb3  = (const float*)d_in[38];

    float* out  = (float*)d_out;
    float* out0 = out;                 // radiance 131072*3
    float* out1 = out + 393216;        // srdf 131072
    float* out2 = out + 524288;        // pip 4*3*131072

    float* ws    = (float*)d_ws;
    float* featT = ws + WS_FEATT;
    float* imgT  = ws + WS_IMGT;
    float* x1    = ws + WS_X1;
    float* xr    = ws + WS_XR;
    float* msg   = ws + WS_MSG;
    float* rgbw  = ws + WS_RGB;
    float* dirw  = ws + WS_DIR;
    float* maskw = ws + WS_MASK;

    k0_transpose<<<dim3(1024), dim3(256), 0, stream>>>(feat, imgs, featT, imgT);
    k1_geom_sample<<<dim3(2048), dim3(256), 0, stream>>>(p3d, rpi, spi, sp, featT, imgT,
                                                         x1, rgbw, dirw, maskw, out2);
    k2_loftr1<<<dim3(2048), dim3(256), 0, stream>>>(x1, vtok, vtWq, vtWk, vtWv, vtWm,
                                                    vtg1, vtb1, vtW1, vtW2, vtg2, vtb2, xr);
    k3a_attn<<<dim3(1024), dim3(320), 0, stream>>>(xr, rtWq, rtWk, rtWv, rtWm, rtg1, rtb1, msg);
    k3b_ffn<<<dim3(1024), dim3(320), 0, stream>>>(xr, msg, rtW1, rtW2, rtg2, rtb2);
    k4_dm<<<dim3(512), dim3(256), 0, stream>>>(xr, dmW1, dmb1, dmW2, dmb2, dmW3, dmb3, out1);
    k5_rw<<<dim3(512), dim3(256), 0, stream>>>(x1, dirw, maskw, rgbw,
                                               rwW1, rwb1, rwW2, rwb2, rwW3, rwb3, out0);
}